// Round 1
// baseline (27.356 us; speedup 1.0000x reference)
//
#include <hip/hip_runtime.h>

#define NK 8
#define NR 32
#define NF 16
#define NB 32768
#define PPS 64   // floats per (k,r) param record: [0:16)=mu, [16:32)=0.5/sig^2, [32:48)=w, [48]=bias

// Pre-pack params into ws: one thread per (k,r,f).
__global__ void hfnn_prep(const float* __restrict__ mu,
                          const float* __restrict__ sg,
                          const float* __restrict__ w3,
                          float* __restrict__ pp) {
    int t = blockIdx.x * blockDim.x + threadIdx.x;
    if (t >= NK * NR * NF) return;
    int kr = t >> 4, f = t & 15;
    float* rec = pp + (size_t)kr * PPS;
    float s = sg[t];
    rec[f]      = mu[t];
    rec[16 + f] = 0.5f / (s * s);
    rec[32 + f] = w3[kr * (NF + 1) + f];
    if (f == 0) rec[48] = w3[kr * (NF + 1) + NF];
}

// Block = 512 threads = 8 waves; wave w handles branch k=w for 64 batch elems.
__global__ __launch_bounds__(512) void hfnn_main(const float* __restrict__ data,
                                                 const float* __restrict__ pp,
                                                 const float* __restrict__ w5,
                                                 const float* __restrict__ b5,
                                                 float* __restrict__ out) {
    __shared__ float tl[NK][64];
    const int lane = threadIdx.x & 63;
    // readfirstlane -> compiler proves k wave-uniform -> param loads become s_load
    const int k = __builtin_amdgcn_readfirstlane((int)(threadIdx.x >> 6));
    const int b = blockIdx.x * 64 + lane;

    // x: 64B contiguous per thread, coalesced across the wave
    const float* xp = data + ((size_t)k * NB + b) * NF;
    float x[NF];
#pragma unroll
    for (int i = 0; i < 4; ++i)
        reinterpret_cast<float4*>(x)[i] = reinterpret_cast<const float4*>(xp)[i];

    const float* base = pp + (size_t)k * NR * PPS;
    float num = 0.f, den = 0.f;
#pragma unroll 2
    for (int r = 0; r < NR; ++r) {
        const float* rec = base + r * PPS;   // wave-uniform -> SGPR loads
        float expo = 0.f;
        float conq = rec[48];
#pragma unroll
        for (int f = 0; f < NF; ++f) {
            float d = x[f] - rec[f];
            expo = fmaf(d * d, rec[16 + f], expo);
            conq = fmaf(x[f], rec[32 + f], conq);
        }
        float e = __expf(-expo);
        num = fmaf(e, conq, num);
        den += e;
    }
    tl[k][lane] = __fdividef(num, den);   // tsk[k][b]
    __syncthreads();

    if (threadIdx.x < 64) {  // wave 0: combine branches, softmax over 2 classes
        float l0 = b5[0], l1 = b5[1];
#pragma unroll
        for (int kk = 0; kk < NK; ++kk) {
            float t = tl[kk][lane];
            l0 = fmaf(t, w5[kk], l0);        // w5[0][kk]
            l1 = fmaf(t, w5[NK + kk], l1);   // w5[1][kk]
        }
        float m = fmaxf(l0, l1);
        float e0 = __expf(l0 - m);
        float e1 = __expf(l1 - m);
        float inv = __fdividef(1.f, e0 + e1);
        float2 o = make_float2(e0 * inv, e1 * inv);
        *reinterpret_cast<float2*>(out + (size_t)(blockIdx.x * 64 + lane) * 2) = o;
    }
}

extern "C" void kernel_launch(void* const* d_in, const int* in_sizes, int n_in,
                              void* d_out, int out_size, void* d_ws, size_t ws_size,
                              hipStream_t stream) {
    const float* data = (const float*)d_in[0];
    const float* mu   = (const float*)d_in[1];
    const float* sg   = (const float*)d_in[2];
    const float* w3   = (const float*)d_in[3];
    const float* w5   = (const float*)d_in[4];
    const float* b5   = (const float*)d_in[5];
    float* out = (float*)d_out;
    float* pp  = (float*)d_ws;   // 8*32*64*4 = 64 KB

    hfnn_prep<<<(NK * NR * NF + 255) / 256, 256, 0, stream>>>(mu, sg, w3, pp);
    hfnn_main<<<NB / 64, 512, 0, stream>>>(data, pp, w5, b5, out);
}

// Round 2
// 22.018 us; speedup vs baseline: 1.2424x; 1.2424x over previous
//
#include <hip/hip_runtime.h>

#define NK 8
#define NR 32
#define NF 16
#define NB 32768
#define RSTR 52   // floats per rule record in LDS: [0:16)=A, [16:32)=B, [32:48)=w, [48]=C, [49]=bias

__device__ __forceinline__ float fexp2(float v) {
#if __has_builtin(__builtin_amdgcn_exp2f)
    return __builtin_amdgcn_exp2f(v);
#else
    return __expf(v * 0.6931471805599453f);
#endif
}

// One fused kernel. Block = 512 = 8 waves; wave w <-> branch k=w, 64 batch elems per block.
__global__ __launch_bounds__(512, 4) void hfnn_fused(
    const float* __restrict__ data, const float* __restrict__ mu,
    const float* __restrict__ sg,   const float* __restrict__ w3,
    const float* __restrict__ w5,   const float* __restrict__ b5,
    float* __restrict__ out)
{
    __shared__ __align__(16) float prm[NK][NR * RSTR];   // 53248 B
    __shared__ float tl[NK][64];                          // 2048 B

    const int lane = threadIdx.x & 63;
    const int k    = threadIdx.x >> 6;                    // wave id == branch

    // ---- stage folded params into this wave's LDS slice (no barrier needed:
    //      each wave reads only what it wrote; compiler tracks lgkmcnt) ----
#pragma unroll
    for (int pass = 0; pass < 8; ++pass) {
        const int r  = pass * 4 + ((lane >> 4) & 3);
        const int f  = lane & 15;
        const int kr = k * NR + r;
        float muv = mu[kr * NF + f];
        float sv  = sg[kr * NF + f];
        float wv  = w3[kr * (NF + 1) + f];
        float inv2s = 0.5f / (sv * sv);
        float A  = -1.4426950408889634f * inv2s;   // -log2(e)/(2 sigma^2)
        float B  = -2.0f * muv * A;
        float Cp = A * muv * muv;
        Cp += __shfl_xor(Cp, 1, 16);
        Cp += __shfl_xor(Cp, 2, 16);
        Cp += __shfl_xor(Cp, 4, 16);
        Cp += __shfl_xor(Cp, 8, 16);
        float* rec = &prm[k][r * RSTR];
        rec[f]          = A;
        rec[NF + f]     = B;
        rec[2 * NF + f] = wv;
        if (f == 0) { rec[48] = Cp; rec[49] = w3[kr * (NF + 1) + NF]; }
    }

    // ---- per-thread batch element ----
    const int b = blockIdx.x * 64 + lane;
    const float* xp = data + ((size_t)k * NB + b) * NF;
    float x[NF];
#pragma unroll
    for (int i = 0; i < 4; ++i)
        reinterpret_cast<float4*>(x)[i] = reinterpret_cast<const float4*>(xp)[i];

    float num = 0.f, den = 0.f;

#pragma unroll 2
    for (int r = 0; r < NR; ++r) {
        const float4* r4 = reinterpret_cast<const float4*>(&prm[k][r * RSTR]);
        float4 A0 = r4[0], A1 = r4[1], A2 = r4[2], A3 = r4[3];
        float4 B0 = r4[4], B1 = r4[5], B2 = r4[6], B3 = r4[7];
        float4 W0 = r4[8], W1 = r4[9], W2 = r4[10], W3 = r4[11];
        float2 cb = *reinterpret_cast<const float2*>(&prm[k][r * RSTR + 48]);

        float sA0 = cb.x, sA1 = 0.f;         // exponent accumulators (C folded in)
        float cq0 = cb.y, cq1 = 0.f;         // consequent accumulators (bias folded in)

#define FT(xf, Ac, Bc, Wc, sA, cq)                     \
        sA = fmaf(xf, fmaf(xf, Ac, Bc), sA);           \
        cq = fmaf(xf, Wc, cq);

        FT(x[0],  A0.x, B0.x, W0.x, sA0, cq0)
        FT(x[1],  A0.y, B0.y, W0.y, sA1, cq1)
        FT(x[2],  A0.z, B0.z, W0.z, sA0, cq0)
        FT(x[3],  A0.w, B0.w, W0.w, sA1, cq1)
        FT(x[4],  A1.x, B1.x, W1.x, sA0, cq0)
        FT(x[5],  A1.y, B1.y, W1.y, sA1, cq1)
        FT(x[6],  A1.z, B1.z, W1.z, sA0, cq0)
        FT(x[7],  A1.w, B1.w, W1.w, sA1, cq1)
        FT(x[8],  A2.x, B2.x, W2.x, sA0, cq0)
        FT(x[9],  A2.y, B2.y, W2.y, sA1, cq1)
        FT(x[10], A2.z, B2.z, W2.z, sA0, cq0)
        FT(x[11], A2.w, B2.w, W2.w, sA1, cq1)
        FT(x[12], A3.x, B3.x, W3.x, sA0, cq0)
        FT(x[13], A3.y, B3.y, W3.y, sA1, cq1)
        FT(x[14], A3.z, B3.z, W3.z, sA0, cq0)
        FT(x[15], A3.w, B3.w, W3.w, sA1, cq1)
#undef FT

        float e = fexp2(sA0 + sA1);
        num = fmaf(e, cq0 + cq1, num);
        den += e;
    }

    tl[k][lane] = __fdividef(num, den);      // tsk[k][b]
    __syncthreads();

    if (threadIdx.x < 64) {                  // wave 0: branch combine + 2-class softmax
        float l0 = b5[0], l1 = b5[1];
#pragma unroll
        for (int kk = 0; kk < NK; ++kk) {
            float t = tl[kk][lane];
            l0 = fmaf(t, w5[kk],      l0);
            l1 = fmaf(t, w5[NK + kk], l1);
        }
        float m  = fmaxf(l0, l1);
        float e0 = __expf(l0 - m);
        float e1 = __expf(l1 - m);
        float inv = __fdividef(1.f, e0 + e1);
        *reinterpret_cast<float2*>(out + (size_t)(blockIdx.x * 64 + lane) * 2) =
            make_float2(e0 * inv, e1 * inv);
    }
}

extern "C" void kernel_launch(void* const* d_in, const int* in_sizes, int n_in,
                              void* d_out, int out_size, void* d_ws, size_t ws_size,
                              hipStream_t stream) {
    const float* data = (const float*)d_in[0];
    const float* mu   = (const float*)d_in[1];
    const float* sg   = (const float*)d_in[2];
    const float* w3   = (const float*)d_in[3];
    const float* w5   = (const float*)d_in[4];
    const float* b5   = (const float*)d_in[5];
    float* out = (float*)d_out;

    hfnn_fused<<<NB / 64, 512, 0, stream>>>(data, mu, sg, w3, w5, b5, out);
}